// Round 6
// baseline (261.034 us; speedup 1.0000x reference)
//
#include <hip/hip_runtime.h>
#include <math.h>

#define BB 4
#define SS 4096
#define DD 1024
#define HH 16
#define GG 4
#define KK 3
#define DG 256
#define DH 64
#define CH 16            // s-rows per zxw / out chunk
#define NCH (SS / CH)    // 256 chunks per batch

// ---- workspace layout (float offsets, all float4-aligned) ----
enum : size_t {
  OFF_WEFF  = 0,        // unused (Weff recomputed in-block)
  OFF_OFFC  = 1024,     // 4 (pad 256)
  OFF_WEQ   = 1280,     // 12*DD = 12288
  OFF_ZT    = 13568,    // unused (zt now block-local LDS)
  OFF_WX    = 210176,   // B*G*S = 65536
  OFF_XWP   = 275712,   // B*5*NCH*DD = 5242880 [b][slot][chunk][c]
  OFF_XW    = 5518592,  // B*G*D = 16384
  OFF_XS    = 5534976,  // B*D = 4096
  OFF_SW    = 5539072,  // 16 (pad 256) -- zeroed in k_pre, atomicAdd in k_zxw
  OFF_FEAT  = 5539328,  // unused (feat inlined into Kf/Vf)
  OFF_KF    = 5543424,  // B*G*D = 16384 [b][g][o]
  OFF_VF    = 5559808,  // B*G*D = 16384
  OFF_AV    = 5576192,  // B*D*G = 16384 [b][d][g]
  OFF_AB    = 5592576,  // B*D = 4096
  OFF_C2    = 5596672,  // B*D = 4096
  OFF_WAV   = 5600768,  // B*D*G = 16384 [b][o][g]
  OFF_WOSUM = 5617152,  // D = 1024
  WS_FLOATS = 5618176   // ~22.5 MB
};

__device__ __forceinline__ float wred_sum(float v) {
#pragma unroll
  for (int o = 32; o > 0; o >>= 1) v += __shfl_xor(v, o, 64);
  return v;
}
__device__ __forceinline__ float wred_max(float v) {
#pragma unroll
  for (int o = 32; o > 0; o >>= 1) v = fmaxf(v, __shfl_xor(v, o, 64));
  return v;
}

// ---- k_pre: Weq (blocks 0..191, 16 per j), offc+SW-zero (192),
//             Kf/Vf inline-feat (193..1216), WoSum (1217..1472) ----
// R5 fix: Weq stages get independent accumulator chains + deeper unroll
// (R5 showed 47us latency tail: 1 acc chain -> <=4 loads in flight).
__global__ __launch_bounds__(256) void k_pre(
    const float* __restrict__ x,  const float* __restrict__ Wq, const float* __restrict__ bq,
    const float* __restrict__ Wk, const float* __restrict__ Wv, const float* __restrict__ Wo,
    const float* __restrict__ Woff1, const float* __restrict__ boff1,
    const float* __restrict__ Woff2, float* __restrict__ ws) {
  const int t = threadIdx.x;
  const int lane = t & 63;
  const int wv = t >> 6;
  const int bid = blockIdx.x;
  __shared__ float weff_sh[256];
  __shared__ float red[4][64];

  if (bid < 192) {                               // Weq[j][c0..c0+63]
    const int j = bid >> 4;                      // 0..11
    const int c0 = (bid & 15) * 64;
    const int g = j / 3, kk = j - 3 * g;
    // stage 1: weff_sh[i=t] via 4 independent cc-quarter chains (MLP)
    float a0 = 0.f, a1 = 0.f, a2 = 0.f, a3 = 0.f;
#pragma unroll 8
    for (int u = 0; u < 64; ++u) {
      a0 += Woff2[u]       * Woff1[(size_t)((u)       * DG + t) * KK + kk];
      a1 += Woff2[u + 64]  * Woff1[(size_t)((u + 64)  * DG + t) * KK + kk];
      a2 += Woff2[u + 128] * Woff1[(size_t)((u + 128) * DG + t) * KK + kk];
      a3 += Woff2[u + 192] * Woff1[(size_t)((u + 192) * DG + t) * KK + kk];
    }
    weff_sh[t] = (a0 + a1) + (a2 + a3);
    __syncthreads();
    // stage 2: 2 independent chains per wave (i halves), unroll 8
    float b0 = 0.f, b1 = 0.f;
#pragma unroll 8
    for (int ii = 0; ii < 32; ++ii) {
      const int i = wv * 64 + ii;
      b0 += weff_sh[i]      * Wq[(size_t)(g * DG + i)      * DD + c0 + lane];
      b1 += weff_sh[i + 32] * Wq[(size_t)(g * DG + i + 32) * DD + c0 + lane];
    }
    red[wv][lane] = b0 + b1;
    __syncthreads();
    if (wv == 0) {
      const float v = red[0][lane] + red[1][lane] + red[2][lane] + red[3][lane];
      ws[OFF_WEQ + (size_t)j * DD + c0 + lane] = v;
    }
  } else if (bid == 192) {                       // offc[g] + SW zero-init
    if (t < 16) ws[OFF_SW + t] = 0.f;
    float accs = 0.f;
#pragma unroll 4
    for (int cc = 0; cc < DG; ++cc) {
      const float* w1 = Woff1 + (size_t)(cc * DG + t) * KK;
      accs += Woff2[cc] * (w1[0] + w1[1] + w1[2]);
    }
    float be = Woff2[t] * boff1[t];              // beff partial (t spans 256 channels)
    be = wred_sum(be);
    if (lane == 0) weff_sh[wv] = be;
    __syncthreads();
    const float beff = weff_sh[0] + weff_sh[1] + weff_sh[2] + weff_sh[3];
#pragma unroll
    for (int g = 0; g < 4; ++g) {
      float a = accs * bq[g * DG + t];           // weffsum[t] * bq[g*DG+t]
      a = wred_sum(a);
      if (lane == 0) red[g][wv] = a;
    }
    __syncthreads();
    if (t < 4)
      ws[OFF_OFFC + t] = red[t][0] + red[t][1] + red[t][2] + red[t][3] + beff;
  } else if (bid < 1217) {                       // Kf/Vf: wave per (g,o), feat inlined
    const int widx = (bid - 193) * 4 + wv;       // 0..4095
    const int g = widx >> 10, o = widx & 1023;
    const float4 ak  = ((const float4*)(Wk + (size_t)o * DD + g * DG))[lane];
    const float4 avv = ((const float4*)(Wv + (size_t)o * DD + g * DG))[lane];
    float kk4[4], vv4[4];
#pragma unroll
    for (int b = 0; b < 4; ++b) {                // feat = 0.5*(x[s=2047]+x[s=2048])
      const float4 xa = ((const float4*)(x + ((size_t)b * SS + 2047) * DD + g * DG))[lane];
      const float4 xb = ((const float4*)(x + ((size_t)b * SS + 2048) * DD + g * DG))[lane];
      const float fx = 0.5f * (xa.x + xb.x), fy = 0.5f * (xa.y + xb.y);
      const float fz = 0.5f * (xa.z + xb.z), fw = 0.5f * (xa.w + xb.w);
      kk4[b] = ak.x * fx + ak.y * fy + ak.z * fz + ak.w * fw;
      vv4[b] = avv.x * fx + avv.y * fy + avv.z * fz + avv.w * fw;
    }
#pragma unroll
    for (int b = 0; b < 4; ++b) { kk4[b] = wred_sum(kk4[b]); vv4[b] = wred_sum(vv4[b]); }
    if (lane == 0) {
#pragma unroll
      for (int b = 0; b < 4; ++b) {
        ws[OFF_KF + ((size_t)(b * GG + g)) * DD + o] = kk4[b];
        ws[OFF_VF + ((size_t)(b * GG + g)) * DD + o] = vv4[b];
      }
    }
  } else {                                       // WoSum[o]: wave per o
    const int o = (bid - 1217) * 4 + wv;         // 0..1023
    const float4* wo = (const float4*)(Wo + (size_t)o * DD);
    float v = 0.f;
#pragma unroll
    for (int it = 0; it < 4; ++it) {
      const float4 a = wo[lane + 64 * it];
      v += a.x + a.y + a.z + a.w;
    }
    v = wred_sum(v);
    if (lane == 0) ws[OFF_WOSUM + o] = v;
  }
}

// ---- k_zxw: per (b, chunk): 18 local zt rows in LDS, then wx + partial sums.
// R5 fix: phase A register-blocked (6 weq fragments at a time, acc[5][12])
// -- the old w[12][4]=192-float cache couldn't fit 128 VGPRs and was being
// reloaded every row. Per-j reduction order unchanged (bit-identical). ----
__global__ __launch_bounds__(256, 2) void k_zxw(const float* __restrict__ x,
                                                float* __restrict__ ws) {
  const int t = threadIdx.x;
  const int lane = t & 63;
  const int wv = t >> 6;
  const int b = blockIdx.x >> 8;
  const int chunk = blockIdx.x & 255;
  const int s0 = chunk * CH;
  __shared__ float zl[18][12];                   // zt rows s0-1 .. s0+16
  __shared__ float wxs[64];                      // wx[g][si]

  // phase A: z-dots, register-blocked. Wave wv owns rows r = wv+4q (q=0..4).
  {
    const float* weq = ws + OFF_WEQ;
    float acc[5][12];
#pragma unroll
    for (int q = 0; q < 5; ++q)
#pragma unroll
      for (int j = 0; j < 12; ++j) acc[q][j] = 0.f;
#pragma unroll
    for (int jh = 0; jh < 2; ++jh) {
#pragma unroll
      for (int it = 0; it < 4; ++it) {
        float4 wj[6];
#pragma unroll
        for (int j6 = 0; j6 < 6; ++j6)
          wj[j6] = *(const float4*)(weq + (size_t)(jh * 6 + j6) * DD + 4 * (lane + 64 * it));
#pragma unroll
        for (int q = 0; q < 5; ++q) {
          const int r = wv + 4 * q;
          const int s = s0 - 1 + r;
          if (r < 18 && s >= 0 && s < SS) {
            const float4 xv = *((const float4*)(x + ((size_t)b * SS + s) * DD) + (lane + 64 * it));
#pragma unroll
            for (int j6 = 0; j6 < 6; ++j6)
              acc[q][jh * 6 + j6] += xv.x * wj[j6].x + xv.y * wj[j6].y +
                                     xv.z * wj[j6].z + xv.w * wj[j6].w;
          }
        }
      }
    }
#pragma unroll
    for (int q = 0; q < 5; ++q) {
      const int r = wv + 4 * q;
      const int s = s0 - 1 + r;
      if (r < 18 && s >= 0 && s < SS) {
#pragma unroll
        for (int j = 0; j < 12; ++j) {
          const float v = wred_sum(acc[q][j]);
          if (lane == 0) zl[r][j] = v;
        }
      }
    }
  }
  __syncthreads();

  // phase B: offsets -> wx (row s maps to zl[si+1])
  if (t < 64) {
    const int g = t >> 4, si = t & 15;
    const int s = s0 + si;
    float off = ws[OFF_OFFC + g];
    if (s > 0)      off += zl[si][g * 3 + 0];
    off += zl[si + 1][g * 3 + 1];
    if (s < SS - 1) off += zl[si + 2][g * 3 + 2];
    off = tanhf(off) * (float)KK;
    const float vg = 2.0f * ((float)s + off) / (float)(SS - 1) - 1.0f;
    float wvv = 1.0f - fabsf(0.5f * vg);
    wvv = fminf(fmaxf(wvv, 0.0f), 1.0f);
    wxs[t] = wvv;
    ws[OFF_WX + (size_t)(b * GG + g) * SS + s] = wvv;
  }
  __syncthreads();

  if (t < 4) {                                   // Sw partial (atomic; SW zeroed in k_pre)
    float sl = 0.f;
#pragma unroll
    for (int si = 0; si < 16; ++si) sl += wxs[t * 16 + si];
    atomicAdd(&ws[OFF_SW + b * GG + t], sl);
  }

  // phase C: weighted partial sums over the 16 rows (x re-read is L1/L2-hot)
  float4 aw[5] = {};
#pragma unroll 4
  for (int si = 0; si < CH; ++si) {
    const int s = s0 + si;
    const float4 f = *(const float4*)(x + (size_t)(b * SS + s) * DD + 4 * t);
    const float w0 = wxs[si], w1 = wxs[16 + si], w2 = wxs[32 + si], w3 = wxs[48 + si];
    aw[0].x += f.x * w0; aw[0].y += f.y * w0; aw[0].z += f.z * w0; aw[0].w += f.w * w0;
    aw[1].x += f.x * w1; aw[1].y += f.y * w1; aw[1].z += f.z * w1; aw[1].w += f.w * w1;
    aw[2].x += f.x * w2; aw[2].y += f.y * w2; aw[2].z += f.z * w2; aw[2].w += f.w * w2;
    aw[3].x += f.x * w3; aw[3].y += f.y * w3; aw[3].z += f.z * w3; aw[3].w += f.w * w3;
    aw[4].x += f.x; aw[4].y += f.y; aw[4].z += f.z; aw[4].w += f.w;
  }
#pragma unroll
  for (int slot = 0; slot < 5; ++slot)
    *(float4*)(ws + OFF_XWP + (((size_t)(b * 5 + slot) * NCH + chunk) * DD) + 4 * t) = aw[slot];
}

// ---- k_red: reduce XWP -> XW / XS (320 blocks) ----
__global__ void k_red(float* __restrict__ ws) {
  const int t = threadIdx.x;
  const int lane = t & 63;
  const int wvid = t >> 6;
  __shared__ float red[4][64];
  const int rb = blockIdx.x / 80;
  const int rem = blockIdx.x - rb * 80;
  const int slot = rem >> 4;
  const int c = (rem & 15) * 64 + lane;
  const float* base = ws + OFF_XWP + (size_t)(rb * 5 + slot) * NCH * DD;
  float a = 0.f;
#pragma unroll 8
  for (int ii = 0; ii < 64; ++ii)
    a += base[(size_t)(wvid * 64 + ii) * DD + c];
  red[wvid][lane] = a;
  __syncthreads();
  if (wvid == 0) {
    const float v = red[0][lane] + red[1][lane] + red[2][lane] + red[3][lane];
    if (slot < 4) ws[OFF_XW + ((size_t)(rb * GG + slot)) * DD + c] = v;
    else          ws[OFF_XS + (size_t)rb * DD + c] = v;
  }
}

// ---- k_mid: Qw/Qs dots fused with attention. Wave per (b, I=d). ----
__global__ void k_mid(const float* __restrict__ Wq, const float* __restrict__ bq,
                      const float* __restrict__ bk, const float* __restrict__ bv,
                      float* __restrict__ ws) {
  const int t = threadIdx.x;
  const int lane = t & 63;
  const int wave = blockIdx.x * 4 + (t >> 6);    // 0..4095
  const int ab_ = wave >> 10, I = wave & 1023;
  const float4* wq = (const float4*)(Wq + (size_t)I * DD);
  float4 a[4];
#pragma unroll
  for (int it = 0; it < 4; ++it) a[it] = wq[lane + 64 * it];
  float acc[5] = {0.f, 0.f, 0.f, 0.f, 0.f};
#pragma unroll
  for (int g = 0; g < 4; ++g) {
    const float4* xw = (const float4*)(ws + OFF_XW + (size_t)(ab_ * GG + g) * DD);
#pragma unroll
    for (int it = 0; it < 4; ++it) {
      const float4 c = xw[lane + 64 * it];
      acc[g] += a[it].x * c.x + a[it].y * c.y + a[it].z * c.z + a[it].w * c.w;
    }
  }
  const float4* xs = (const float4*)(ws + OFF_XS + (size_t)ab_ * DD);
#pragma unroll
  for (int it = 0; it < 4; ++it) {
    const float4 c = xs[lane + 64 * it];
    acc[4] += a[it].x * c.x + a[it].y * c.y + a[it].z * c.z + a[it].w * c.w;
  }
#pragma unroll
  for (int u = 0; u < 5; ++u) acc[u] = wred_sum(acc[u]);
  const float bqi = bq[I];
  const float q0 = acc[0] + bqi * ws[OFF_SW + ab_ * GG + 0];
  const float q1 = acc[1] + bqi * ws[OFF_SW + ab_ * GG + 1];
  const float q2 = acc[2] + bqi * ws[OFF_SW + ab_ * GG + 2];
  const float q3 = acc[3] + bqi * ws[OFF_SW + ab_ * GG + 3];
  const float qs = acc[4] + (float)SS * bqi;
  const int J = (I & ~63) | lane;
  const float* Kf = ws + OFF_KF + (size_t)ab_ * GG * DD;
  float sc = q0 * Kf[0 * DD + J] + q1 * Kf[1 * DD + J] +
             q2 * Kf[2 * DD + J] + q3 * Kf[3 * DD + J] + bk[J] * qs;
  sc *= 0.03125f;                                // D^-0.5
  const float m = wred_max(sc);
  const float e = expf(sc - m);
  const float sum = wred_sum(e);
  const float attn = e / sum;
  const float* Vf = ws + OFF_VF + (size_t)ab_ * GG * DD;
#pragma unroll
  for (int g = 0; g < 4; ++g) {
    const float av = wred_sum(attn * Vf[(size_t)g * DD + J]);
    if (lane == 0) ws[OFF_AV + (size_t)wave * 4 + g] = av;
  }
  const float abv = wred_sum(attn * bv[J]);
  if (lane == 0) ws[OFF_AB + wave] = abv;
}

// ---- k_wav: WAV[b,o,g] = sum_d Wo[o,d]*AV[b,d,g]; C2 = sum_d Wo*Ab + bo ----
__global__ void k_wav(const float* __restrict__ Wo, const float* __restrict__ bo,
                      float* __restrict__ ws) {
  const int gid = blockIdx.x * blockDim.x + threadIdx.x;
  const int lane = gid & 63;
  const int w = gid >> 6;                        // w = b*1024 + o
  if (w >= BB * DD) return;
  const int b = w >> 10, o = w & 1023;
  float acc0 = 0, acc1 = 0, acc2 = 0, acc3 = 0, acc4 = 0;
  const float4* wo4 = (const float4*)(Wo + (size_t)o * DD);
  const float* AV = ws + OFF_AV + (size_t)b * DD * 4;
  const float* Ab = ws + OFF_AB + (size_t)b * DD;
#pragma unroll
  for (int it = 0; it < 4; ++it) {
    const int d4 = lane + 64 * it;
    const float4 wv4 = wo4[d4];
    const float4 a0 = *(const float4*)(AV + (size_t)(4 * d4 + 0) * 4);
    const float4 a1 = *(const float4*)(AV + (size_t)(4 * d4 + 1) * 4);
    const float4 a2 = *(const float4*)(AV + (size_t)(4 * d4 + 2) * 4);
    const float4 a3 = *(const float4*)(AV + (size_t)(4 * d4 + 3) * 4);
    acc0 += wv4.x * a0.x + wv4.y * a1.x + wv4.z * a2.x + wv4.w * a3.x;
    acc1 += wv4.x * a0.y + wv4.y * a1.y + wv4.z * a2.y + wv4.w * a3.y;
    acc2 += wv4.x * a0.z + wv4.y * a1.z + wv4.z * a2.z + wv4.w * a3.z;
    acc3 += wv4.x * a0.w + wv4.y * a1.w + wv4.z * a2.w + wv4.w * a3.w;
    const float4 abv = *(const float4*)(Ab + 4 * d4);
    acc4 += wv4.x * abv.x + wv4.y * abv.y + wv4.z * abv.z + wv4.w * abv.w;
  }
  acc0 = wred_sum(acc0); acc1 = wred_sum(acc1); acc2 = wred_sum(acc2);
  acc3 = wred_sum(acc3); acc4 = wred_sum(acc4);
  if (lane == 0) {
    float* WAV = ws + OFF_WAV + (size_t)w * 4;
    WAV[0] = acc0; WAV[1] = acc1; WAV[2] = acc2; WAV[3] = acc3;
    ws[OFF_C2 + w] = acc4 + bo[o];
  }
}

// ---- k_out: out[b,s,o] = sum_g wx*WAV + C2 + bias_table[s]*WoSum ----
__global__ __launch_bounds__(256) void k_out(const float* __restrict__ btab,
                                             const float* __restrict__ ws,
                                             float* __restrict__ out) {
  const int b = blockIdx.x >> 8;
  const int ch = blockIdx.x & 255;
  const int t = threadIdx.x;
  const int o0 = 4 * t;
  float4 wav[4];
#pragma unroll
  for (int io = 0; io < 4; ++io)
    wav[io] = *(const float4*)(ws + OFF_WAV + (size_t)(b * DD + o0 + io) * 4);
  const float4 c24  = *(const float4*)(ws + OFF_C2 + (size_t)b * DD + o0);
  const float4 wos4 = *(const float4*)(ws + OFF_WOSUM + o0);
  const float* wx = ws + OFF_WX;
  const int s0 = ch * CH;
#pragma unroll 2
  for (int si = 0; si < CH; ++si) {
    const int s = s0 + si;
    const float w0 = wx[(size_t)(b * GG + 0) * SS + s];
    const float w1 = wx[(size_t)(b * GG + 1) * SS + s];
    const float w2 = wx[(size_t)(b * GG + 2) * SS + s];
    const float w3 = wx[(size_t)(b * GG + 3) * SS + s];
    const float bt = btab[s];
    float4 val;
    val.x = c24.x + bt * wos4.x + w0 * wav[0].x + w1 * wav[0].y + w2 * wav[0].z + w3 * wav[0].w;
    val.y = c24.y + bt * wos4.y + w0 * wav[1].x + w1 * wav[1].y + w2 * wav[1].z + w3 * wav[1].w;
    val.z = c24.z + bt * wos4.z + w0 * wav[2].x + w1 * wav[2].y + w2 * wav[2].z + w3 * wav[2].w;
    val.w = c24.w + bt * wos4.w + w0 * wav[3].x + w1 * wav[3].y + w2 * wav[3].z + w3 * wav[3].w;
    *(float4*)(out + (size_t)(b * SS + s) * DD + o0) = val;
  }
}

extern "C" void kernel_launch(void* const* d_in, const int* in_sizes, int n_in,
                              void* d_out, int out_size, void* d_ws, size_t ws_size,
                              hipStream_t stream) {
  const float* x     = (const float*)d_in[0];
  const float* Wq    = (const float*)d_in[1];
  const float* bq    = (const float*)d_in[2];
  const float* Wk    = (const float*)d_in[3];
  const float* bk    = (const float*)d_in[4];
  const float* Wv    = (const float*)d_in[5];
  const float* bv    = (const float*)d_in[6];
  const float* Wo    = (const float*)d_in[7];
  const float* bo    = (const float*)d_in[8];
  const float* Woff1 = (const float*)d_in[9];
  const float* boff1 = (const float*)d_in[10];
  const float* Woff2 = (const float*)d_in[11];
  const float* btab  = (const float*)d_in[12];
  float* ws  = (float*)d_ws;
  float* out = (float*)d_out;

  k_pre<<<1473, 256, 0, stream>>>(x, Wq, bq, Wk, Wv, Wo, Woff1, boff1, Woff2, ws);
  k_zxw<<<1024, 256, 0, stream>>>(x, ws);
  k_red<<<320, 256, 0, stream>>>(ws);
  k_mid<<<1024, 256, 0, stream>>>(Wq, bq, bk, bv, ws);
  k_wav<<<1024, 256, 0, stream>>>(Wo, bo, ws);
  k_out<<<1024, 256, 0, stream>>>(btab, ws, out);
}

// Round 8
// 213.511 us; speedup vs baseline: 1.2226x; 1.2226x over previous
//
#include <hip/hip_runtime.h>
#include <math.h>

#define BB 4
#define SS 4096
#define DD 1024
#define HH 16
#define GG 4
#define KK 3
#define DG 256
#define DH 64
#define CH 16            // s-rows per zxw / out chunk
#define NCH (SS / CH)    // 256 chunks per batch

typedef float v4f __attribute__((ext_vector_type(4)));  // for nontemporal stores

// ---- workspace layout (float offsets, all float4-aligned) ----
enum : size_t {
  OFF_WEFF  = 0,        // unused (Weff recomputed in-block)
  OFF_OFFC  = 1024,     // 4 (pad 256)
  OFF_WEQ   = 1280,     // 12*DD = 12288
  OFF_ZT    = 13568,    // unused (zt now block-local LDS)
  OFF_WX    = 210176,   // B*G*S = 65536
  OFF_XWP   = 275712,   // B*5*NCH*DD = 5242880 [b][slot][chunk][c]
  OFF_XW    = 5518592,  // B*G*D = 16384
  OFF_XS    = 5534976,  // B*D = 4096
  OFF_SW    = 5539072,  // 16 (pad 256) -- zeroed in k_pre, atomicAdd in k_zxw
  OFF_FEAT  = 5539328,  // unused (feat inlined into Kf/Vf)
  OFF_KF    = 5543424,  // B*G*D = 16384 [b][g][o]
  OFF_VF    = 5559808,  // B*G*D = 16384
  OFF_AV    = 5576192,  // B*D*G = 16384 [b][d][g]
  OFF_AB    = 5592576,  // B*D = 4096
  OFF_C2    = 5596672,  // B*D = 4096
  OFF_WAV   = 5600768,  // B*D*G = 16384 [b][o][g]
  OFF_WOSUM = 5617152,  // D = 1024
  WS_FLOATS = 5618176   // ~22.5 MB
};

__device__ __forceinline__ float wred_sum(float v) {
#pragma unroll
  for (int o = 32; o > 0; o >>= 1) v += __shfl_xor(v, o, 64);
  return v;
}
__device__ __forceinline__ float wred_max(float v) {
#pragma unroll
  for (int o = 32; o > 0; o >>= 1) v = fmaxf(v, __shfl_xor(v, o, 64));
  return v;
}

// ---- k_pre: Weq only (blocks 0..191) + offc/SW-zero (192). Critical-path
// kernel shrunk: Kf/Vf and WoSum moved into the k_zxw dispatch (independent
// work, not needed until k_mid / k_out). ----
__global__ __launch_bounds__(256) void k_pre(
    const float* __restrict__ Wq, const float* __restrict__ bq,
    const float* __restrict__ Woff1, const float* __restrict__ boff1,
    const float* __restrict__ Woff2, float* __restrict__ ws) {
  const int t = threadIdx.x;
  const int lane = t & 63;
  const int wv = t >> 6;
  const int bid = blockIdx.x;
  __shared__ float weff_sh[256];
  __shared__ float red[4][64];

  if (bid < 192) {                               // Weq[j][c0..c0+63]
    const int j = bid >> 4;                      // 0..11
    const int c0 = (bid & 15) * 64;
    const int g = j / 3, kk = j - 3 * g;
    // stage 1: weff_sh[i=t] via 4 independent cc-quarter chains (MLP)
    float a0 = 0.f, a1 = 0.f, a2 = 0.f, a3 = 0.f;
#pragma unroll 8
    for (int u = 0; u < 64; ++u) {
      a0 += Woff2[u]       * Woff1[(size_t)((u)       * DG + t) * KK + kk];
      a1 += Woff2[u + 64]  * Woff1[(size_t)((u + 64)  * DG + t) * KK + kk];
      a2 += Woff2[u + 128] * Woff1[(size_t)((u + 128) * DG + t) * KK + kk];
      a3 += Woff2[u + 192] * Woff1[(size_t)((u + 192) * DG + t) * KK + kk];
    }
    weff_sh[t] = (a0 + a1) + (a2 + a3);
    __syncthreads();
    // stage 2: 2 independent chains per wave (i halves), unroll 8
    float b0 = 0.f, b1 = 0.f;
#pragma unroll 8
    for (int ii = 0; ii < 32; ++ii) {
      const int i = wv * 64 + ii;
      b0 += weff_sh[i]      * Wq[(size_t)(g * DG + i)      * DD + c0 + lane];
      b1 += weff_sh[i + 32] * Wq[(size_t)(g * DG + i + 32) * DD + c0 + lane];
    }
    red[wv][lane] = b0 + b1;
    __syncthreads();
    if (wv == 0) {
      const float v = red[0][lane] + red[1][lane] + red[2][lane] + red[3][lane];
      ws[OFF_WEQ + (size_t)j * DD + c0 + lane] = v;
    }
  } else {                                       // offc[g] + SW zero-init
    if (t < 16) ws[OFF_SW + t] = 0.f;
    float accs = 0.f;
#pragma unroll 4
    for (int cc = 0; cc < DG; ++cc) {
      const float* w1 = Woff1 + (size_t)(cc * DG + t) * KK;
      accs += Woff2[cc] * (w1[0] + w1[1] + w1[2]);
    }
    float be = Woff2[t] * boff1[t];              // beff partial (t spans 256 channels)
    be = wred_sum(be);
    if (lane == 0) weff_sh[wv] = be;
    __syncthreads();
    const float beff = weff_sh[0] + weff_sh[1] + weff_sh[2] + weff_sh[3];
#pragma unroll
    for (int g = 0; g < 4; ++g) {
      float a = accs * bq[g * DG + t];           // weffsum[t] * bq[g*DG+t]
      a = wred_sum(a);
      if (lane == 0) red[g][wv] = a;
    }
    __syncthreads();
    if (t < 4)
      ws[OFF_OFFC + t] = red[t][0] + red[t][1] + red[t][2] + red[t][3] + beff;
  }
}

// ---- k_zxw: blocks [0,1024): Kf/Vf (independent, scheduled first)
//             blocks [1024,1280): WoSum (independent)
//             blocks [1280,2304): z-dots (18-row LDS halo) + wx + partial sums
// Phase A/B/C bodies are the exact R5 version (45.8 us proven); R6's
// register-blocked variant re-read x twice (FETCH 57->88MB) and regressed. ----
__global__ __launch_bounds__(256, 2) void k_zxw(const float* __restrict__ x,
                                                const float* __restrict__ Wk,
                                                const float* __restrict__ Wv,
                                                const float* __restrict__ Wo,
                                                float* __restrict__ ws) {
  const int t = threadIdx.x;
  const int lane = t & 63;
  const int wv = t >> 6;
  const int bid = blockIdx.x;
  __shared__ float zl[18][12];                   // zt rows s0-1 .. s0+16
  __shared__ float wxs[64];                      // wx[g][si]

  if (bid < 1024) {                              // Kf/Vf: wave per (g,o), feat inlined
    const int widx = bid * 4 + wv;               // 0..4095
    const int g = widx >> 10, o = widx & 1023;
    const float4 ak  = ((const float4*)(Wk + (size_t)o * DD + g * DG))[lane];
    const float4 avv = ((const float4*)(Wv + (size_t)o * DD + g * DG))[lane];
    float kk4[4], vv4[4];
#pragma unroll
    for (int b = 0; b < 4; ++b) {                // feat = 0.5*(x[s=2047]+x[s=2048])
      const float4 xa = ((const float4*)(x + ((size_t)b * SS + 2047) * DD + g * DG))[lane];
      const float4 xb = ((const float4*)(x + ((size_t)b * SS + 2048) * DD + g * DG))[lane];
      const float fx = 0.5f * (xa.x + xb.x), fy = 0.5f * (xa.y + xb.y);
      const float fz = 0.5f * (xa.z + xb.z), fw = 0.5f * (xa.w + xb.w);
      kk4[b] = ak.x * fx + ak.y * fy + ak.z * fz + ak.w * fw;
      vv4[b] = avv.x * fx + avv.y * fy + avv.z * fz + avv.w * fw;
    }
#pragma unroll
    for (int b = 0; b < 4; ++b) { kk4[b] = wred_sum(kk4[b]); vv4[b] = wred_sum(vv4[b]); }
    if (lane == 0) {
#pragma unroll
      for (int b = 0; b < 4; ++b) {
        ws[OFF_KF + ((size_t)(b * GG + g)) * DD + o] = kk4[b];
        ws[OFF_VF + ((size_t)(b * GG + g)) * DD + o] = vv4[b];
      }
    }
    return;
  } else if (bid < 1280) {                       // WoSum[o]: wave per o
    const int o = (bid - 1024) * 4 + wv;         // 0..1023
    const float4* wo = (const float4*)(Wo + (size_t)o * DD);
    float v = 0.f;
#pragma unroll
    for (int it = 0; it < 4; ++it) {
      const float4 a = wo[lane + 64 * it];
      v += a.x + a.y + a.z + a.w;
    }
    v = wred_sum(v);
    if (lane == 0) ws[OFF_WOSUM + o] = v;
    return;
  }

  const int zbid = bid - 1280;
  const int b = zbid >> 8;
  const int chunk = zbid & 255;
  const int s0 = chunk * CH;

  // phase A: z-dots, wave per row (R5 exact)
  {
    const float* weq = ws + OFF_WEQ;
    float4 w[12][4];
#pragma unroll
    for (int j = 0; j < 12; ++j)
#pragma unroll
      for (int it = 0; it < 4; ++it)
        w[j][it] = *(const float4*)(weq + (size_t)j * DD + 4 * (lane + 64 * it));
    for (int r = wv; r < 18; r += 4) {
      const int s = s0 - 1 + r;
      if (s < 0 || s >= SS) continue;
      const float4* xr = (const float4*)(x + ((size_t)b * SS + s) * DD);
      float4 xv[4];
#pragma unroll
      for (int it = 0; it < 4; ++it) xv[it] = xr[lane + 64 * it];
      float acc[12];
#pragma unroll
      for (int j = 0; j < 12; ++j) {
        float a = 0.f;
#pragma unroll
        for (int it = 0; it < 4; ++it)
          a += xv[it].x * w[j][it].x + xv[it].y * w[j][it].y +
               xv[it].z * w[j][it].z + xv[it].w * w[j][it].w;
        acc[j] = a;
      }
#pragma unroll
      for (int j = 0; j < 12; ++j) acc[j] = wred_sum(acc[j]);
      if (lane == 0) {
#pragma unroll
        for (int j = 0; j < 12; ++j) zl[r][j] = acc[j];
      }
    }
  }
  __syncthreads();

  // phase B: offsets -> wx (row s maps to zl[si+1])
  if (t < 64) {
    const int g = t >> 4, si = t & 15;
    const int s = s0 + si;
    float off = ws[OFF_OFFC + g];
    if (s > 0)      off += zl[si][g * 3 + 0];
    off += zl[si + 1][g * 3 + 1];
    if (s < SS - 1) off += zl[si + 2][g * 3 + 2];
    off = tanhf(off) * (float)KK;
    const float vg = 2.0f * ((float)s + off) / (float)(SS - 1) - 1.0f;
    float wvv = 1.0f - fabsf(0.5f * vg);
    wvv = fminf(fmaxf(wvv, 0.0f), 1.0f);
    wxs[t] = wvv;
    ws[OFF_WX + (size_t)(b * GG + g) * SS + s] = wvv;
  }
  __syncthreads();

  if (t < 4) {                                   // Sw partial (atomic; SW zeroed in k_pre)
    float sl = 0.f;
#pragma unroll
    for (int si = 0; si < 16; ++si) sl += wxs[t * 16 + si];
    atomicAdd(&ws[OFF_SW + b * GG + t], sl);
  }

  // phase C: weighted partial sums over the 16 rows (x re-read is L1/L2-hot)
  float4 aw[5] = {};
#pragma unroll 4
  for (int si = 0; si < CH; ++si) {
    const int s = s0 + si;
    const float4 f = *(const float4*)(x + (size_t)(b * SS + s) * DD + 4 * t);
    const float w0 = wxs[si], w1 = wxs[16 + si], w2 = wxs[32 + si], w3 = wxs[48 + si];
    aw[0].x += f.x * w0; aw[0].y += f.y * w0; aw[0].z += f.z * w0; aw[0].w += f.w * w0;
    aw[1].x += f.x * w1; aw[1].y += f.y * w1; aw[1].z += f.z * w1; aw[1].w += f.w * w1;
    aw[2].x += f.x * w2; aw[2].y += f.y * w2; aw[2].z += f.z * w2; aw[2].w += f.w * w2;
    aw[3].x += f.x * w3; aw[3].y += f.y * w3; aw[3].z += f.z * w3; aw[3].w += f.w * w3;
    aw[4].x += f.x; aw[4].y += f.y; aw[4].z += f.z; aw[4].w += f.w;
  }
#pragma unroll
  for (int slot = 0; slot < 5; ++slot)
    *(float4*)(ws + OFF_XWP + (((size_t)(b * 5 + slot) * NCH + chunk) * DD) + 4 * t) = aw[slot];
}

// ---- k_red: reduce XWP -> XW / XS (320 blocks) ----
__global__ void k_red(float* __restrict__ ws) {
  const int t = threadIdx.x;
  const int lane = t & 63;
  const int wvid = t >> 6;
  __shared__ float red[4][64];
  const int rb = blockIdx.x / 80;
  const int rem = blockIdx.x - rb * 80;
  const int slot = rem >> 4;
  const int c = (rem & 15) * 64 + lane;
  const float* base = ws + OFF_XWP + (size_t)(rb * 5 + slot) * NCH * DD;
  float a = 0.f;
#pragma unroll 8
  for (int ii = 0; ii < 64; ++ii)
    a += base[(size_t)(wvid * 64 + ii) * DD + c];
  red[wvid][lane] = a;
  __syncthreads();
  if (wvid == 0) {
    const float v = red[0][lane] + red[1][lane] + red[2][lane] + red[3][lane];
    if (slot < 4) ws[OFF_XW + ((size_t)(rb * GG + slot)) * DD + c] = v;
    else          ws[OFF_XS + (size_t)rb * DD + c] = v;
  }
}

// ---- k_mid: Qw/Qs dots fused with attention. Wave per (b, I=d). ----
__global__ void k_mid(const float* __restrict__ Wq, const float* __restrict__ bq,
                      const float* __restrict__ bk, const float* __restrict__ bv,
                      float* __restrict__ ws) {
  const int t = threadIdx.x;
  const int lane = t & 63;
  const int wave = blockIdx.x * 4 + (t >> 6);    // 0..4095
  const int ab_ = wave >> 10, I = wave & 1023;
  const float4* wq = (const float4*)(Wq + (size_t)I * DD);
  float4 a[4];
#pragma unroll
  for (int it = 0; it < 4; ++it) a[it] = wq[lane + 64 * it];
  float acc[5] = {0.f, 0.f, 0.f, 0.f, 0.f};
#pragma unroll
  for (int g = 0; g < 4; ++g) {
    const float4* xw = (const float4*)(ws + OFF_XW + (size_t)(ab_ * GG + g) * DD);
#pragma unroll
    for (int it = 0; it < 4; ++it) {
      const float4 c = xw[lane + 64 * it];
      acc[g] += a[it].x * c.x + a[it].y * c.y + a[it].z * c.z + a[it].w * c.w;
    }
  }
  const float4* xs = (const float4*)(ws + OFF_XS + (size_t)ab_ * DD);
#pragma unroll
  for (int it = 0; it < 4; ++it) {
    const float4 c = xs[lane + 64 * it];
    acc[4] += a[it].x * c.x + a[it].y * c.y + a[it].z * c.z + a[it].w * c.w;
  }
#pragma unroll
  for (int u = 0; u < 5; ++u) acc[u] = wred_sum(acc[u]);
  const float bqi = bq[I];
  const float q0 = acc[0] + bqi * ws[OFF_SW + ab_ * GG + 0];
  const float q1 = acc[1] + bqi * ws[OFF_SW + ab_ * GG + 1];
  const float q2 = acc[2] + bqi * ws[OFF_SW + ab_ * GG + 2];
  const float q3 = acc[3] + bqi * ws[OFF_SW + ab_ * GG + 3];
  const float qs = acc[4] + (float)SS * bqi;
  const int J = (I & ~63) | lane;
  const float* Kf = ws + OFF_KF + (size_t)ab_ * GG * DD;
  float sc = q0 * Kf[0 * DD + J] + q1 * Kf[1 * DD + J] +
             q2 * Kf[2 * DD + J] + q3 * Kf[3 * DD + J] + bk[J] * qs;
  sc *= 0.03125f;                                // D^-0.5
  const float m = wred_max(sc);
  const float e = expf(sc - m);
  const float sum = wred_sum(e);
  const float attn = e / sum;
  const float* Vf = ws + OFF_VF + (size_t)ab_ * GG * DD;
#pragma unroll
  for (int g = 0; g < 4; ++g) {
    const float av = wred_sum(attn * Vf[(size_t)g * DD + J]);
    if (lane == 0) ws[OFF_AV + (size_t)wave * 4 + g] = av;
  }
  const float abv = wred_sum(attn * bv[J]);
  if (lane == 0) ws[OFF_AB + wave] = abv;
}

// ---- k_wav: WAV[b,o,g] = sum_d Wo[o,d]*AV[b,d,g]; C2 = sum_d Wo*Ab + bo ----
__global__ void k_wav(const float* __restrict__ Wo, const float* __restrict__ bo,
                      float* __restrict__ ws) {
  const int gid = blockIdx.x * blockDim.x + threadIdx.x;
  const int lane = gid & 63;
  const int w = gid >> 6;                        // w = b*1024 + o
  if (w >= BB * DD) return;
  const int b = w >> 10, o = w & 1023;
  float acc0 = 0, acc1 = 0, acc2 = 0, acc3 = 0, acc4 = 0;
  const float4* wo4 = (const float4*)(Wo + (size_t)o * DD);
  const float* AV = ws + OFF_AV + (size_t)b * DD * 4;
  const float* Ab = ws + OFF_AB + (size_t)b * DD;
#pragma unroll
  for (int it = 0; it < 4; ++it) {
    const int d4 = lane + 64 * it;
    const float4 wv4 = wo4[d4];
    const float4 a0 = *(const float4*)(AV + (size_t)(4 * d4 + 0) * 4);
    const float4 a1 = *(const float4*)(AV + (size_t)(4 * d4 + 1) * 4);
    const float4 a2 = *(const float4*)(AV + (size_t)(4 * d4 + 2) * 4);
    const float4 a3 = *(const float4*)(AV + (size_t)(4 * d4 + 3) * 4);
    acc0 += wv4.x * a0.x + wv4.y * a1.x + wv4.z * a2.x + wv4.w * a3.x;
    acc1 += wv4.x * a0.y + wv4.y * a1.y + wv4.z * a2.y + wv4.w * a3.y;
    acc2 += wv4.x * a0.z + wv4.y * a1.z + wv4.z * a2.z + wv4.w * a3.z;
    acc3 += wv4.x * a0.w + wv4.y * a1.w + wv4.z * a2.w + wv4.w * a3.w;
    const float4 abv = *(const float4*)(Ab + 4 * d4);
    acc4 += wv4.x * abv.x + wv4.y * abv.y + wv4.z * abv.z + wv4.w * abv.w;
  }
  acc0 = wred_sum(acc0); acc1 = wred_sum(acc1); acc2 = wred_sum(acc2);
  acc3 = wred_sum(acc3); acc4 = wred_sum(acc4);
  if (lane == 0) {
    float* WAV = ws + OFF_WAV + (size_t)w * 4;
    WAV[0] = acc0; WAV[1] = acc1; WAV[2] = acc2; WAV[3] = acc3;
    ws[OFF_C2 + w] = acc4 + bo[o];
  }
}

// ---- k_out: out[b,s,o] = sum_g wx*WAV + C2 + bias_table[s]*WoSum ----
// nontemporal stores (via native ext_vector type): out is never re-read.
__global__ __launch_bounds__(256) void k_out(const float* __restrict__ btab,
                                             const float* __restrict__ ws,
                                             float* __restrict__ out) {
  const int b = blockIdx.x >> 8;
  const int ch = blockIdx.x & 255;
  const int t = threadIdx.x;
  const int o0 = 4 * t;
  float4 wav[4];
#pragma unroll
  for (int io = 0; io < 4; ++io)
    wav[io] = *(const float4*)(ws + OFF_WAV + (size_t)(b * DD + o0 + io) * 4);
  const float4 c24  = *(const float4*)(ws + OFF_C2 + (size_t)b * DD + o0);
  const float4 wos4 = *(const float4*)(ws + OFF_WOSUM + o0);
  const float* wx = ws + OFF_WX;
  const int s0 = ch * CH;
#pragma unroll 2
  for (int si = 0; si < CH; ++si) {
    const int s = s0 + si;
    const float w0 = wx[(size_t)(b * GG + 0) * SS + s];
    const float w1 = wx[(size_t)(b * GG + 1) * SS + s];
    const float w2 = wx[(size_t)(b * GG + 2) * SS + s];
    const float w3 = wx[(size_t)(b * GG + 3) * SS + s];
    const float bt = btab[s];
    v4f val;
    val.x = c24.x + bt * wos4.x + w0 * wav[0].x + w1 * wav[0].y + w2 * wav[0].z + w3 * wav[0].w;
    val.y = c24.y + bt * wos4.y + w0 * wav[1].x + w1 * wav[1].y + w2 * wav[1].z + w3 * wav[1].w;
    val.z = c24.z + bt * wos4.z + w0 * wav[2].x + w1 * wav[2].y + w2 * wav[2].z + w3 * wav[2].w;
    val.w = c24.w + bt * wos4.w + w0 * wav[3].x + w1 * wav[3].y + w2 * wav[3].z + w3 * wav[3].w;
    __builtin_nontemporal_store(val, (v4f*)(out + (size_t)(b * SS + s) * DD + o0));
  }
}

extern "C" void kernel_launch(void* const* d_in, const int* in_sizes, int n_in,
                              void* d_out, int out_size, void* d_ws, size_t ws_size,
                              hipStream_t stream) {
  const float* x     = (const float*)d_in[0];
  const float* Wq    = (const float*)d_in[1];
  const float* bq    = (const float*)d_in[2];
  const float* Wk    = (const float*)d_in[3];
  const float* bk    = (const float*)d_in[4];
  const float* Wv    = (const float*)d_in[5];
  const float* bv    = (const float*)d_in[6];
  const float* Wo    = (const float*)d_in[7];
  const float* bo    = (const float*)d_in[8];
  const float* Woff1 = (const float*)d_in[9];
  const float* boff1 = (const float*)d_in[10];
  const float* Woff2 = (const float*)d_in[11];
  const float* btab  = (const float*)d_in[12];
  float* ws  = (float*)d_ws;
  float* out = (float*)d_out;

  k_pre<<<193, 256, 0, stream>>>(Wq, bq, Woff1, boff1, Woff2, ws);
  k_zxw<<<2304, 256, 0, stream>>>(x, Wk, Wv, Wo, ws);
  k_red<<<320, 256, 0, stream>>>(ws);
  k_mid<<<1024, 256, 0, stream>>>(Wq, bq, bk, bv, ws);
  k_wav<<<1024, 256, 0, stream>>>(Wo, bo, ws);
  k_out<<<1024, 256, 0, stream>>>(btab, ws, out);
}